// Round 4
// baseline (132.111 us; speedup 1.0000x reference)
//
#include <hip/hip_runtime.h>

#define NUM_ROWS 500000
#define TERMS 164
#define KSTEPS 6                       // 6 * 32 = 192 k-slots (164 terms + bias@164 + pad)
#define NFRAG (KSTEPS * 4)             // 24 weight fragments, each 64 lanes x uint4
#define NITER ((NUM_ROWS + 63) / 64)   // 7813 (last iter: 32 rows)

typedef __attribute__((ext_vector_type(8))) short bf16x8;
typedef __attribute__((ext_vector_type(4))) float f32x4;
typedef __attribute__((ext_vector_type(4))) unsigned int uint4v;

// ---------------------------------------------------------------------------
// Compile-time replica of the reference exponent-table construction
// (verified round 1: term order matches numpy meshgrid/.T/reshape exactly).
// ---------------------------------------------------------------------------
struct ETab { int e[192][8]; int n; };

constexpr ETab make_et() {
    ETab T{};
    for (int i = 0; i < 192; ++i)
        for (int f = 0; f < 8; ++f) T.e[i][f] = 0;
    T.n = 0;
    for (int a = 0; a <= 3; ++a)                       // e7
     for (int b = 0; a + b <= 3; ++b)                  // e6
      for (int c = 0; a + b + c <= 3; ++c)             // e5
       for (int d = 0; a + b + c + d <= 3; ++d)        // e4
        for (int e_ = 0; a + b + c + d + e_ <= 3; ++e_)            // e3
         for (int f_ = 0; a + b + c + d + e_ + f_ <= 3; ++f_)      // e2
          for (int g = 0; a + b + c + d + e_ + f_ + g <= 3; ++g)   // e0
           for (int h = 0; a + b + c + d + e_ + f_ + g + h <= 3; ++h) { // e1
               int s = a + b + c + d + e_ + f_ + g + h;
               if (s >= 1) {
                   T.e[T.n][0] = g;  T.e[T.n][1] = h;
                   T.e[T.n][2] = f_; T.e[T.n][3] = e_;
                   T.e[T.n][4] = d;  T.e[T.n][5] = c;
                   T.e[T.n][6] = b;  T.e[T.n][7] = a;
                   ++T.n;
               }
           }
    return T;
}

static_assert(make_et().n == TERMS, "term count must be 164");
__device__ constexpr ETab ET = make_et();

// RNE float->bf16 pack of two floats into one dword (verified round 1,
// absmax 0.25; finite inputs only).
__device__ __forceinline__ unsigned int pack2bf(float a, float b) {
    unsigned int ua = __float_as_uint(a), ub = __float_as_uint(b);
    ua = ua + 0x7fffu + ((ua >> 16) & 1u);
    ub = ub + 0x7fffu + ((ub >> 16) & 1u);
    return (ua >> 16) | (ub & 0xffff0000u);
}

// Basis term value; t is compile-time constant after unrolling, so ET loads
// and degree branches fold away (<=2 v_mul_f32 per term). Slot 164 is the
// bias slot: basis value 1.0 for every row (weight side carries bias[j]).
__device__ __forceinline__ float term_val(int t, const float (&p1)[8],
                                          const float (&p2)[8],
                                          const float (&p3)[8]) {
    if (t > TERMS) return 0.f;
    if (t == TERMS) return 1.f;
    float v = 1.f;
#pragma unroll
    for (int f = 0; f < 8; ++f) {
        const int d = ET.e[t][f];
        if (d == 1) v *= p1[f];
        else if (d == 2) v *= p2[f];
        else if (d == 3) v *= p3[f];
    }
    return v;
}

// Weight-side value for k-slot t of output column j (runtime t, staging only).
__device__ __forceinline__ float wval(const float* __restrict__ w,
                                      const float* __restrict__ b,
                                      int j, int t) {
    if (t < TERMS) return w[j * TERMS + t];
    if (t == TERMS) return b[j];
    return 0.f;
}

// Pre-pack weight A-fragments into d_ws: fragment p = ks*4+ct, per lane 4
// dwords. Lane (kq,i): A[row = ct*16+i][k = kq*8 + {2dw, 2dw+1}].
__global__ __launch_bounds__(256) void pack_weights_kernel(
        const float* __restrict__ weight, const float* __restrict__ bias,
        unsigned int* __restrict__ wpack) {
    int idx = blockIdx.x * 256 + threadIdx.x;
    if (idx >= NFRAG * 256) return;
    int p    = idx >> 8;
    int lane = (idx >> 2) & 63;
    int dw   = idx & 3;
    int ks = p >> 2, ct = p & 3;
    int kq = lane >> 4;
    int j  = (ct << 4) | (lane & 15);          // output column 0..63
    int t0 = ks * 32 + kq * 8 + dw * 2;
    wpack[idx] = pack2bf(wval(weight, bias, j, t0), wval(weight, bias, j, t0 + 1));
}

// ---------------------------------------------------------------------------
// Main body. Each lane owns one row; per ks it computes its row's 32 terms,
// writes 4 packed chunks to per-wave LDS, reads back B-fragments (row/kq
// transpose), and runs 16 MFMAs (4 ct x 4 q). D = W * basis^T, so each
// lane's 4 acc elements are 4 consecutive out columns -> float4 stores.
// Same-wave DS ordering makes the LDS exchange barrier-free.
// PLAIN stores (round-3 lesson: nontemporal 64B partial-line stores bypass
// L2 write-combining -> 3.3x write amplification + RMW fetches).
// ---------------------------------------------------------------------------
__device__ __forceinline__ void poly_body(const float* __restrict__ x,
                                          const uint4v* __restrict__ bsrc,
                                          float* __restrict__ out,
                                          uint4v (&sT)[4][4][64]) {
    const int tid  = threadIdx.x;
    const int lane = tid & 63;
    const int wid  = tid >> 6;
    const int m    = lane & 15;
    const int kq   = lane >> 4;

    const int gw = blockIdx.x * 4 + wid;
    const int nw = gridDim.x * 4;

    for (int it = gw; it < NITER; it += nw) {
        const int rbase = it * 64;
        const int myrow = rbase + lane;

        float4 xa = {0.f, 0.f, 0.f, 0.f}, xb = {0.f, 0.f, 0.f, 0.f};
        if (myrow < NUM_ROWS) {
            const float4* xp = (const float4*)(x + (size_t)myrow * 8);
            xa = xp[0]; xb = xp[1];
        }
        float p1[8], p2[8], p3[8];
        p1[0] = xa.x; p1[1] = xa.y; p1[2] = xa.z; p1[3] = xa.w;
        p1[4] = xb.x; p1[5] = xb.y; p1[6] = xb.z; p1[7] = xb.w;
#pragma unroll
        for (int f = 0; f < 8; ++f) {
            p2[f] = p1[f] * p1[f];
            p3[f] = p2[f] * p1[f];
        }

        f32x4 acc[4][4];   // [ct][q]
#pragma unroll
        for (int ct = 0; ct < 4; ++ct)
#pragma unroll
            for (int q = 0; q < 4; ++q)
                acc[ct][q] = (f32x4){0.f, 0.f, 0.f, 0.f};

#pragma unroll
        for (int ks = 0; ks < KSTEPS; ++ks) {
            // --- my row's 32 terms for this ks, packed into 4 uint4 chunks ---
#pragma unroll
            for (int c = 0; c < 4; ++c) {
                uint4v ch;
#pragma unroll
                for (int d = 0; d < 4; ++d) {
                    float a = term_val(ks * 32 + c * 8 + d * 2,     p1, p2, p3);
                    float b = term_val(ks * 32 + c * 8 + d * 2 + 1, p1, p2, p3);
                    ch[d] = pack2bf(a, b);
                }
                sT[wid][c][lane] = ch;   // row/kq transpose via per-wave LDS
            }

            // --- weight A-fragments (uniform across waves; L2-resident) ---
            uint4v aw[4];
#pragma unroll
            for (int ct = 0; ct < 4; ++ct)
                aw[ct] = bsrc[(ks * 4 + ct) * 64 + lane];

            // --- B-fragments from LDS + 16 MFMAs ---
#pragma unroll
            for (int q = 0; q < 4; ++q) {
                uint4v bw = sT[wid][kq][q * 16 + m];
                bf16x8 bfrag = __builtin_bit_cast(bf16x8, bw);
#pragma unroll
                for (int ct = 0; ct < 4; ++ct) {
                    bf16x8 afrag = __builtin_bit_cast(bf16x8, aw[ct]);
                    acc[ct][q] = __builtin_amdgcn_mfma_f32_16x16x32_bf16(
                                     afrag, bfrag, acc[ct][q], 0, 0, 0);
                }
            }
        }

        // --- epilogue: D[i=out-col kq*4+r][j=row m] -> float4 per (ct,q) ---
#pragma unroll
        for (int q = 0; q < 4; ++q) {
            const int orow = rbase + q * 16 + m;
            if (orow < NUM_ROWS) {
#pragma unroll
                for (int ct = 0; ct < 4; ++ct) {
                    f32x4* po = (f32x4*)(out + (size_t)orow * 64 + ct * 16 + kq * 4);
                    *po = acc[ct][q];
                }
            }
        }
    }
}

__global__ __launch_bounds__(256, 4) void poly_ws_kernel(
        const float* __restrict__ x, const unsigned int* __restrict__ wpack,
        float* __restrict__ out) {
    __shared__ uint4v sT[4][4][64];   // 16 KiB
    poly_body(x, (const uint4v*)wpack, out, sT);
}

// Fallback if d_ws is too small: stage weight fragments in LDS instead.
__global__ __launch_bounds__(256, 4) void poly_lds_kernel(
        const float* __restrict__ x, const float* __restrict__ weight,
        const float* __restrict__ bias, float* __restrict__ out) {
    __shared__ uint4v sT[4][4][64];          // 16 KiB
    __shared__ unsigned int sB[NFRAG * 256]; // 24 KiB
    const int tid = threadIdx.x;
#pragma unroll 1
    for (int idx = tid; idx < NFRAG * 256; idx += 256) {
        int p = idx >> 8, lane = (idx >> 2) & 63, dw = idx & 3;
        int ks = p >> 2, ct = p & 3, kq = lane >> 4;
        int j  = (ct << 4) | (lane & 15);
        int t0 = ks * 32 + kq * 8 + dw * 2;
        sB[idx] = pack2bf(wval(weight, bias, j, t0), wval(weight, bias, j, t0 + 1));
    }
    __syncthreads();
    poly_body(x, (const uint4v*)sB, out, sT);
}

extern "C" void kernel_launch(void* const* d_in, const int* in_sizes, int n_in,
                              void* d_out, int out_size, void* d_ws, size_t ws_size,
                              hipStream_t stream) {
    const float* x      = (const float*)d_in[0];   // 500000 x 8
    const float* weight = (const float*)d_in[1];   // 64 x 164
    const float* bias   = (const float*)d_in[2];   // 64
    float* out          = (float*)d_out;           // 500000 x 64

    if (ws_size >= (size_t)(NFRAG * 256 * sizeof(unsigned int))) {
        unsigned int* wpack = (unsigned int*)d_ws;
        pack_weights_kernel<<<NFRAG, 256, 0, stream>>>(weight, bias, wpack);
        poly_ws_kernel<<<2048, 256, 0, stream>>>(x, wpack, out);
    } else {
        poly_lds_kernel<<<1024, 256, 0, stream>>>(x, weight, bias, out);
    }
}

// Round 6
// 124.509 us; speedup vs baseline: 1.0611x; 1.0611x over previous
//
#include <hip/hip_runtime.h>

#define NUM_ROWS 500000
#define TERMS 164
#define KSTEPS 6                       // 6 * 32 = 192 k-slots (164 terms + bias@164 + pad)
#define NFRAG (KSTEPS * 4)             // 24 weight fragments, each 64 lanes x uint4
#define NITER ((NUM_ROWS + 63) / 64)   // 7813 (last iter: 32 rows)
#define SOSTRIDE 68                    // padded row stride (words) for transpose buf

typedef __attribute__((ext_vector_type(8))) short bf16x8;
typedef __attribute__((ext_vector_type(4))) float f32x4;
typedef __attribute__((ext_vector_type(4))) unsigned int uint4v;

// ---------------------------------------------------------------------------
// Compile-time replica of the reference exponent-table construction
// (verified round 1: term order matches numpy meshgrid/.T/reshape exactly).
// ---------------------------------------------------------------------------
struct ETab { int e[192][8]; int n; };

constexpr ETab make_et() {
    ETab T{};
    for (int i = 0; i < 192; ++i)
        for (int f = 0; f < 8; ++f) T.e[i][f] = 0;
    T.n = 0;
    for (int a = 0; a <= 3; ++a)                       // e7
     for (int b = 0; a + b <= 3; ++b)                  // e6
      for (int c = 0; a + b + c <= 3; ++c)             // e5
       for (int d = 0; a + b + c + d <= 3; ++d)        // e4
        for (int e_ = 0; a + b + c + d + e_ <= 3; ++e_)            // e3
         for (int f_ = 0; a + b + c + d + e_ + f_ <= 3; ++f_)      // e2
          for (int g = 0; a + b + c + d + e_ + f_ + g <= 3; ++g)   // e0
           for (int h = 0; a + b + c + d + e_ + f_ + g + h <= 3; ++h) { // e1
               int s = a + b + c + d + e_ + f_ + g + h;
               if (s >= 1) {
                   T.e[T.n][0] = g;  T.e[T.n][1] = h;
                   T.e[T.n][2] = f_; T.e[T.n][3] = e_;
                   T.e[T.n][4] = d;  T.e[T.n][5] = c;
                   T.e[T.n][6] = b;  T.e[T.n][7] = a;
                   ++T.n;
               }
           }
    return T;
}

static_assert(make_et().n == TERMS, "term count must be 164");
__device__ constexpr ETab ET = make_et();

// RNE float->bf16 pack of two floats into one dword (verified rounds 1/3/4).
__device__ __forceinline__ unsigned int pack2bf(float a, float b) {
    unsigned int ua = __float_as_uint(a), ub = __float_as_uint(b);
    ua = ua + 0x7fffu + ((ua >> 16) & 1u);
    ub = ub + 0x7fffu + ((ub >> 16) & 1u);
    return (ua >> 16) | (ub & 0xffff0000u);
}

// Basis term value; t is compile-time constant after unrolling, so ET loads
// and degree branches fold away (<=2 v_mul_f32 per term). Slot 164 is the
// bias slot: basis value 1.0 for every row (weight side carries bias[j]).
__device__ __forceinline__ float term_val(int t, const float (&p1)[8],
                                          const float (&p2)[8],
                                          const float (&p3)[8]) {
    if (t > TERMS) return 0.f;
    if (t == TERMS) return 1.f;
    float v = 1.f;
#pragma unroll
    for (int f = 0; f < 8; ++f) {
        const int d = ET.e[t][f];
        if (d == 1) v *= p1[f];
        else if (d == 2) v *= p2[f];
        else if (d == 3) v *= p3[f];
    }
    return v;
}

// Weight-side value for k-slot t of output column j (runtime t, staging only).
__device__ __forceinline__ float wval(const float* __restrict__ w,
                                      const float* __restrict__ b,
                                      int j, int t) {
    if (t < TERMS) return w[j * TERMS + t];
    if (t == TERMS) return b[j];
    return 0.f;
}

// Pre-pack weight A-fragments into d_ws: fragment p = ks*4+ct, per lane 4
// dwords. Lane (kq,i): A[row = ct*16+i][k = kq*8 + {2dw, 2dw+1}].
__global__ __launch_bounds__(256) void pack_weights_kernel(
        const float* __restrict__ weight, const float* __restrict__ bias,
        unsigned int* __restrict__ wpack) {
    int idx = blockIdx.x * 256 + threadIdx.x;
    if (idx >= NFRAG * 256) return;
    int p    = idx >> 8;
    int lane = (idx >> 2) & 63;
    int dw   = idx & 3;
    int ks = p >> 2, ct = p & 3;
    int kq = lane >> 4;
    int j  = (ct << 4) | (lane & 15);          // output column 0..63
    int t0 = ks * 32 + kq * 8 + dw * 2;
    wpack[idx] = pack2bf(wval(weight, bias, j, t0), wval(weight, bias, j, t0 + 1));
}

// ---------------------------------------------------------------------------
// Main body — compute identical to VERIFIED round 4 (A=weights, B=basis;
// passed, absmax 0.25). acc[ct][q][r] = out[row rbase+q*16+m][col ct*16+kq*4+r].
//
// Epilogue REPLACED: round 4's direct f32x4 stores (16B/lane @ 256B stride)
// measured 3.2x write amplification + RMW fetches (WRITE 400MB, FETCH 137MB).
// Now: per q-block, transpose the 16x64 result tile through per-wave LDS
// (row stride 68 words -> b128 ops at the conflict-free floor), then store
// with 16 consecutive lanes covering each full 256B output row.
// Same-wave DS ordering -> no barriers (pattern proven rounds 3/4).
// ---------------------------------------------------------------------------
__device__ __forceinline__ void poly_body(const float* __restrict__ x,
                                          const uint4v* __restrict__ bsrc,
                                          float* __restrict__ out,
                                          uint4v (&sT)[4][4][64],
                                          f32x4 (&sO4)[4][16 * SOSTRIDE / 4]) {
    const int tid  = threadIdx.x;
    const int lane = tid & 63;
    const int wid  = tid >> 6;
    const int m    = lane & 15;
    const int kq   = lane >> 4;

    const int gw = blockIdx.x * 4 + wid;
    const int nw = gridDim.x * 4;

    float* sO = (float*)&sO4[wid][0];

    for (int it = gw; it < NITER; it += nw) {
        const int rbase = it * 64;
        const int myrow = rbase + lane;

        float4 xa = {0.f, 0.f, 0.f, 0.f}, xb = {0.f, 0.f, 0.f, 0.f};
        if (myrow < NUM_ROWS) {
            const float4* xp = (const float4*)(x + (size_t)myrow * 8);
            xa = xp[0]; xb = xp[1];
        }
        float p1[8], p2[8], p3[8];
        p1[0] = xa.x; p1[1] = xa.y; p1[2] = xa.z; p1[3] = xa.w;
        p1[4] = xb.x; p1[5] = xb.y; p1[6] = xb.z; p1[7] = xb.w;
#pragma unroll
        for (int f = 0; f < 8; ++f) {
            p2[f] = p1[f] * p1[f];
            p3[f] = p2[f] * p1[f];
        }

        f32x4 acc[4][4];   // [ct][q]
#pragma unroll
        for (int ct = 0; ct < 4; ++ct)
#pragma unroll
            for (int q = 0; q < 4; ++q)
                acc[ct][q] = (f32x4){0.f, 0.f, 0.f, 0.f};

#pragma unroll
        for (int ks = 0; ks < KSTEPS; ++ks) {
            // --- my row's 32 terms for this ks, packed into 4 uint4 chunks ---
#pragma unroll
            for (int c = 0; c < 4; ++c) {
                uint4v ch;
#pragma unroll
                for (int d = 0; d < 4; ++d) {
                    float a = term_val(ks * 32 + c * 8 + d * 2,     p1, p2, p3);
                    float b = term_val(ks * 32 + c * 8 + d * 2 + 1, p1, p2, p3);
                    ch[d] = pack2bf(a, b);
                }
                sT[wid][c][lane] = ch;   // row/kq transpose via per-wave LDS
            }

            // --- weight A-fragments (uniform across waves; L2-resident) ---
            uint4v aw[4];
#pragma unroll
            for (int ct = 0; ct < 4; ++ct)
                aw[ct] = bsrc[(ks * 4 + ct) * 64 + lane];

            // --- basis B-fragments from LDS + 16 MFMAs ---
#pragma unroll
            for (int q = 0; q < 4; ++q) {
                uint4v bw = sT[wid][kq][q * 16 + m];
                bf16x8 bfrag = __builtin_bit_cast(bf16x8, bw);
#pragma unroll
                for (int ct = 0; ct < 4; ++ct) {
                    bf16x8 afrag = __builtin_bit_cast(bf16x8, aw[ct]);
                    acc[ct][q] = __builtin_amdgcn_mfma_f32_16x16x32_bf16(
                                     afrag, bfrag, acc[ct][q], 0, 0, 0);
                }
            }
        }

        // --- epilogue: per q-block, transpose 16x64 tile via LDS, then
        //     store full 256B rows (64 consecutive floats per instr group) ---
#pragma unroll
        for (int q = 0; q < 4; ++q) {
            // write: lane (kq,m) holds row m, feats ct*16+kq*4..+3
#pragma unroll
            for (int ct = 0; ct < 4; ++ct) {
                f32x4* pw = (f32x4*)(sO + m * SOSTRIDE + ct * 16 + kq * 4);
                *pw = acc[ct][q];
            }
            // read rows back feature-major and store coalesced:
            // lane covers row (4g + kq), feats m*4..m*4+3
#pragma unroll
            for (int g = 0; g < 4; ++g) {
                const int R = 4 * g + kq;
                f32x4 v = *(const f32x4*)(sO + R * SOSTRIDE + m * 4);
                const int orow = rbase + q * 16 + R;
                if (orow < NUM_ROWS) {
                    f32x4* po = (f32x4*)(out + (size_t)orow * 64 + m * 4);
                    *po = v;
                }
            }
        }
    }
}

__global__ __launch_bounds__(256, 4) void poly_ws_kernel(
        const float* __restrict__ x, const unsigned int* __restrict__ wpack,
        float* __restrict__ out) {
    __shared__ uint4v sT[4][4][64];                 // 16 KiB
    __shared__ f32x4  sO4[4][16 * SOSTRIDE / 4];    // 17 KiB
    poly_body(x, (const uint4v*)wpack, out, sT, sO4);
}

// Fallback if d_ws is too small: stage weight fragments in LDS instead.
__global__ __launch_bounds__(256, 4) void poly_lds_kernel(
        const float* __restrict__ x, const float* __restrict__ weight,
        const float* __restrict__ bias, float* __restrict__ out) {
    __shared__ uint4v sT[4][4][64];                 // 16 KiB
    __shared__ f32x4  sO4[4][16 * SOSTRIDE / 4];    // 17 KiB
    __shared__ unsigned int sB[NFRAG * 256];        // 24 KiB
    const int tid = threadIdx.x;
#pragma unroll 1
    for (int idx = tid; idx < NFRAG * 256; idx += 256) {
        int p = idx >> 8, lane = (idx >> 2) & 63, dw = idx & 3;
        int ks = p >> 2, ct = p & 3, kq = lane >> 4;
        int j  = (ct << 4) | (lane & 15);
        int t0 = ks * 32 + kq * 8 + dw * 2;
        sB[idx] = pack2bf(wval(weight, bias, j, t0), wval(weight, bias, j, t0 + 1));
    }
    __syncthreads();
    poly_body(x, (const uint4v*)sB, out, sT, sO4);
}

extern "C" void kernel_launch(void* const* d_in, const int* in_sizes, int n_in,
                              void* d_out, int out_size, void* d_ws, size_t ws_size,
                              hipStream_t stream) {
    const float* x      = (const float*)d_in[0];   // 500000 x 8
    const float* weight = (const float*)d_in[1];   // 64 x 164
    const float* bias   = (const float*)d_in[2];   // 64
    float* out          = (float*)d_out;           // 500000 x 64

    if (ws_size >= (size_t)(NFRAG * 256 * sizeof(unsigned int))) {
        unsigned int* wpack = (unsigned int*)d_ws;
        pack_weights_kernel<<<NFRAG, 256, 0, stream>>>(weight, bias, wpack);
        poly_ws_kernel<<<2048, 256, 0, stream>>>(x, wpack, out);
    } else {
        poly_lds_kernel<<<1024, 256, 0, stream>>>(x, weight, bias, out);
    }
}

// Round 7
// 37.042 us; speedup vs baseline: 3.5665x; 3.3613x over previous
//
#include <hip/hip_runtime.h>

#define NUM_ROWS 500000
#define TERMS 164
#define KSTEPS 6                       // 6 * 32 = 192 k-slots (164 terms + bias@164 + pad)
#define NFRAG (KSTEPS * 4)             // 24 weight fragments, each 64 lanes x uint4
#define NITER ((NUM_ROWS + 63) / 64)   // 7813 (last iter: 32 rows)
#define SOSTRIDE 68                    // padded row stride (words) for transpose buf

typedef __attribute__((ext_vector_type(8))) short bf16x8;
typedef __attribute__((ext_vector_type(4))) float f32x4;
typedef __attribute__((ext_vector_type(4))) unsigned int uint4v;

// ---------------------------------------------------------------------------
// Compile-time replica of the reference exponent-table construction
// (verified round 1: term order matches numpy meshgrid/.T/reshape exactly).
// ---------------------------------------------------------------------------
struct ETab { int e[192][8]; int n; };

constexpr ETab make_et() {
    ETab T{};
    for (int i = 0; i < 192; ++i)
        for (int f = 0; f < 8; ++f) T.e[i][f] = 0;
    T.n = 0;
    for (int a = 0; a <= 3; ++a)                       // e7
     for (int b = 0; a + b <= 3; ++b)                  // e6
      for (int c = 0; a + b + c <= 3; ++c)             // e5
       for (int d = 0; a + b + c + d <= 3; ++d)        // e4
        for (int e_ = 0; a + b + c + d + e_ <= 3; ++e_)            // e3
         for (int f_ = 0; a + b + c + d + e_ + f_ <= 3; ++f_)      // e2
          for (int g = 0; a + b + c + d + e_ + f_ + g <= 3; ++g)   // e0
           for (int h = 0; a + b + c + d + e_ + f_ + g + h <= 3; ++h) { // e1
               int s = a + b + c + d + e_ + f_ + g + h;
               if (s >= 1) {
                   T.e[T.n][0] = g;  T.e[T.n][1] = h;
                   T.e[T.n][2] = f_; T.e[T.n][3] = e_;
                   T.e[T.n][4] = d;  T.e[T.n][5] = c;
                   T.e[T.n][6] = b;  T.e[T.n][7] = a;
                   ++T.n;
               }
           }
    return T;
}

static_assert(make_et().n == TERMS, "term count must be 164");
__device__ constexpr ETab ET = make_et();

// RNE float->bf16 pack of two floats into one dword (verified rounds 1/3/4/6).
__device__ __forceinline__ unsigned int pack2bf(float a, float b) {
    unsigned int ua = __float_as_uint(a), ub = __float_as_uint(b);
    ua = ua + 0x7fffu + ((ua >> 16) & 1u);
    ub = ub + 0x7fffu + ((ub >> 16) & 1u);
    return (ua >> 16) | (ub & 0xffff0000u);
}

// Basis term value; t is compile-time constant after unrolling, so ET loads
// and degree branches fold away (<=2 v_mul_f32 per term). Slot 164 is the
// bias slot: basis value 1.0 for every row (weight side carries bias[j]).
__device__ __forceinline__ float term_val(int t, const float (&p1)[8],
                                          const float (&p2)[8],
                                          const float (&p3)[8]) {
    if (t > TERMS) return 0.f;
    if (t == TERMS) return 1.f;
    float v = 1.f;
#pragma unroll
    for (int f = 0; f < 8; ++f) {
        const int d = ET.e[t][f];
        if (d == 1) v *= p1[f];
        else if (d == 2) v *= p2[f];
        else if (d == 3) v *= p3[f];
    }
    return v;
}

// Weight-side value for k-slot t of output column j (runtime t, staging only).
__device__ __forceinline__ float wval(const float* __restrict__ w,
                                      const float* __restrict__ b,
                                      int j, int t) {
    if (t < TERMS) return w[j * TERMS + t];
    if (t == TERMS) return b[j];
    return 0.f;
}

// Pre-pack weight A-fragments into d_ws: fragment p = ks*4+ct, per lane 4
// dwords. Lane (kq,i): A[row = ct*16+i][k = kq*8 + {2dw, 2dw+1}].
__global__ __launch_bounds__(256) void pack_weights_kernel(
        const float* __restrict__ weight, const float* __restrict__ bias,
        unsigned int* __restrict__ wpack) {
    int idx = blockIdx.x * 256 + threadIdx.x;
    if (idx >= NFRAG * 256) return;
    int p    = idx >> 8;
    int lane = (idx >> 2) & 63;
    int dw   = idx & 3;
    int ks = p >> 2, ct = p & 3;
    int kq = lane >> 4;
    int j  = (ct << 4) | (lane & 15);          // output column 0..63
    int t0 = ks * 32 + kq * 8 + dw * 2;
    wpack[idx] = pack2bf(wval(weight, bias, j, t0), wval(weight, bias, j, t0 + 1));
}

// ---------------------------------------------------------------------------
// Main body — compute identical to VERIFIED rounds 4/6 (A=weights, B=basis;
// absmax 0.25). acc[ct][q][r] = out[row rbase+q*16+m][col ct*16+kq*4+r].
//
// ROUND-6 LESSON: __launch_bounds__(256,4) squeezed the allocator to 64
// VGPRs while acc[4][4] alone needs 64 -> accumulators spilled to scratch
// (HBM), causing the 3x WRITE / 137MB FETCH / 3.5% MfmaUtil across rounds
// 3-6 regardless of store pattern. Kernels now use plain
// __launch_bounds__(256): let the allocator take ~130-170 VGPRs, no spill.
//
// Epilogue: per q-block, transpose the 16x64 result tile through per-wave
// LDS (row stride 68 words), then store with 16 consecutive lanes covering
// each full 256B output row (1024B contiguous per instruction).
// Same-wave DS ordering -> no barriers.
// ---------------------------------------------------------------------------
__device__ __forceinline__ void poly_body(const float* __restrict__ x,
                                          const uint4v* __restrict__ bsrc,
                                          float* __restrict__ out,
                                          uint4v (&sT)[4][4][64],
                                          f32x4 (&sO4)[4][16 * SOSTRIDE / 4]) {
    const int tid  = threadIdx.x;
    const int lane = tid & 63;
    const int wid  = tid >> 6;
    const int m    = lane & 15;
    const int kq   = lane >> 4;

    const int gw = blockIdx.x * 4 + wid;
    const int nw = gridDim.x * 4;

    float* sO = (float*)&sO4[wid][0];

    for (int it = gw; it < NITER; it += nw) {
        const int rbase = it * 64;
        const int myrow = rbase + lane;

        float4 xa = {0.f, 0.f, 0.f, 0.f}, xb = {0.f, 0.f, 0.f, 0.f};
        if (myrow < NUM_ROWS) {
            const float4* xp = (const float4*)(x + (size_t)myrow * 8);
            xa = xp[0]; xb = xp[1];
        }
        float p1[8], p2[8], p3[8];
        p1[0] = xa.x; p1[1] = xa.y; p1[2] = xa.z; p1[3] = xa.w;
        p1[4] = xb.x; p1[5] = xb.y; p1[6] = xb.z; p1[7] = xb.w;
#pragma unroll
        for (int f = 0; f < 8; ++f) {
            p2[f] = p1[f] * p1[f];
            p3[f] = p2[f] * p1[f];
        }

        f32x4 acc[4][4];   // [ct][q] — 64 VGPRs, must stay in registers
#pragma unroll
        for (int ct = 0; ct < 4; ++ct)
#pragma unroll
            for (int q = 0; q < 4; ++q)
                acc[ct][q] = (f32x4){0.f, 0.f, 0.f, 0.f};

#pragma unroll
        for (int ks = 0; ks < KSTEPS; ++ks) {
            // --- my row's 32 terms for this ks, packed into 4 uint4 chunks ---
#pragma unroll
            for (int c = 0; c < 4; ++c) {
                uint4v ch;
#pragma unroll
                for (int d = 0; d < 4; ++d) {
                    float a = term_val(ks * 32 + c * 8 + d * 2,     p1, p2, p3);
                    float b = term_val(ks * 32 + c * 8 + d * 2 + 1, p1, p2, p3);
                    ch[d] = pack2bf(a, b);
                }
                sT[wid][c][lane] = ch;   // row/kq transpose via per-wave LDS
            }

            // --- weight A-fragments (uniform across waves; L2-resident) ---
            uint4v aw[4];
#pragma unroll
            for (int ct = 0; ct < 4; ++ct)
                aw[ct] = bsrc[(ks * 4 + ct) * 64 + lane];

            // --- basis B-fragments from LDS + 16 MFMAs ---
#pragma unroll
            for (int q = 0; q < 4; ++q) {
                uint4v bw = sT[wid][kq][q * 16 + m];
                bf16x8 bfrag = __builtin_bit_cast(bf16x8, bw);
#pragma unroll
                for (int ct = 0; ct < 4; ++ct) {
                    bf16x8 afrag = __builtin_bit_cast(bf16x8, aw[ct]);
                    acc[ct][q] = __builtin_amdgcn_mfma_f32_16x16x32_bf16(
                                     afrag, bfrag, acc[ct][q], 0, 0, 0);
                }
            }
        }

        // --- epilogue: per q-block, transpose 16x64 tile via LDS, then
        //     store full 256B rows (1024B contiguous per instruction) ---
#pragma unroll
        for (int q = 0; q < 4; ++q) {
            // write: lane (kq,m) holds row m, feats ct*16+kq*4..+3
#pragma unroll
            for (int ct = 0; ct < 4; ++ct) {
                f32x4* pw = (f32x4*)(sO + m * SOSTRIDE + ct * 16 + kq * 4);
                *pw = acc[ct][q];
            }
            // read rows back feature-major and store coalesced:
            // lane covers row (4g + kq), feats m*4..m*4+3
#pragma unroll
            for (int g = 0; g < 4; ++g) {
                const int R = 4 * g + kq;
                f32x4 v = *(const f32x4*)(sO + R * SOSTRIDE + m * 4);
                const int orow = rbase + q * 16 + R;
                if (orow < NUM_ROWS) {
                    f32x4* po = (f32x4*)(out + (size_t)orow * 64 + m * 4);
                    *po = v;
                }
            }
        }
    }
}

__global__ __launch_bounds__(256) void poly_ws_kernel(
        const float* __restrict__ x, const unsigned int* __restrict__ wpack,
        float* __restrict__ out) {
    __shared__ uint4v sT[4][4][64];                 // 16 KiB
    __shared__ f32x4  sO4[4][16 * SOSTRIDE / 4];    // 17 KiB
    poly_body(x, (const uint4v*)wpack, out, sT, sO4);
}

// Fallback if d_ws is too small: stage weight fragments in LDS instead.
__global__ __launch_bounds__(256) void poly_lds_kernel(
        const float* __restrict__ x, const float* __restrict__ weight,
        const float* __restrict__ bias, float* __restrict__ out) {
    __shared__ uint4v sT[4][4][64];                 // 16 KiB
    __shared__ f32x4  sO4[4][16 * SOSTRIDE / 4];    // 17 KiB
    __shared__ unsigned int sB[NFRAG * 256];        // 24 KiB
    const int tid = threadIdx.x;
#pragma unroll 1
    for (int idx = tid; idx < NFRAG * 256; idx += 256) {
        int p = idx >> 8, lane = (idx >> 2) & 63, dw = idx & 3;
        int ks = p >> 2, ct = p & 3, kq = lane >> 4;
        int j  = (ct << 4) | (lane & 15);
        int t0 = ks * 32 + kq * 8 + dw * 2;
        sB[idx] = pack2bf(wval(weight, bias, j, t0), wval(weight, bias, j, t0 + 1));
    }
    __syncthreads();
    poly_body(x, (const uint4v*)sB, out, sT, sO4);
}

extern "C" void kernel_launch(void* const* d_in, const int* in_sizes, int n_in,
                              void* d_out, int out_size, void* d_ws, size_t ws_size,
                              hipStream_t stream) {
    const float* x      = (const float*)d_in[0];   // 500000 x 8
    const float* weight = (const float*)d_in[1];   // 64 x 164
    const float* bias   = (const float*)d_in[2];   // 64
    float* out          = (float*)d_out;           // 500000 x 64

    if (ws_size >= (size_t)(NFRAG * 256 * sizeof(unsigned int))) {
        unsigned int* wpack = (unsigned int*)d_ws;
        pack_weights_kernel<<<NFRAG, 256, 0, stream>>>(weight, bias, wpack);
        poly_ws_kernel<<<2048, 256, 0, stream>>>(x, wpack, out);
    } else {
        poly_lds_kernel<<<1024, 256, 0, stream>>>(x, weight, bias, out);
    }
}